// Round 7
// baseline (826.640 us; speedup 1.0000x reference)
//
#include <hip/hip_runtime.h>
#include <hip/hip_bf16.h>
#include <cstdint>
#include <cstddef>

// GPTQ int4 linear: out[T,N] = x[T,K] @ dequant(qweight,qzeros,scales)
// T=8192, K=4096, N=11008, GROUP=128.
// Pipeline: x->bf16, dequant->W^T[N,K] bf16, then 256x256-tile 8-wave MFMA GEMM.
// R7: faithful m201 8-phase schedule. Per 2 K-tiles: 8 phases, each
// {ds_read subtile | stage ONE operand-half (2 gloads) | bar | lgkmcnt(0) |
// setprio+16 MFMA | bar}; vmcnt(4) ONLY at phases 4 & 8 (counted, 2 halves
// in flight); stage stream order B0,B1,A0,A1 per tile at phases 4k-5..4k-2.
// Key property: wave (wm,wn) reads only A-half(wm) and B-half(wn>>1), so
// halves free early and in-place overwrite of the live buffer is safe.

#define K_DIM 4096
#define N_DIM 11008
#define GROUP_SZ 128
#define KB (K_DIM * 2)        // bytes per row of a K-major bf16 panel
#define NTILES_K (K_DIM / 64) // 64 K-tiles of BK=64

typedef __bf16 bf16x8_t __attribute__((ext_vector_type(8)));
typedef float f32x4_t __attribute__((ext_vector_type(4)));

__device__ __forceinline__ void async_copy16(const void* g, void* l) {
    __builtin_amdgcn_global_load_lds((const __attribute__((address_space(1))) void*)g,
                                     (__attribute__((address_space(3))) void*)l,
                                     16, 0, 0);
}

// ---------------- x fp32 -> bf16 (vectorized) ----------------
__global__ __launch_bounds__(256) void convert_x_kernel(const float* __restrict__ x,
                                                        __bf16* __restrict__ xb,
                                                        long total) {
    long i = ((long)blockIdx.x * 256 + threadIdx.x) * 8;
    if (i >= total) return;
    const float4* p = (const float4*)(x + i);
    float4 u = p[0], v = p[1];
    bf16x8_t o;
    o[0] = (__bf16)u.x; o[1] = (__bf16)u.y; o[2] = (__bf16)u.z; o[3] = (__bf16)u.w;
    o[4] = (__bf16)v.x; o[5] = (__bf16)v.y; o[6] = (__bf16)v.z; o[7] = (__bf16)v.w;
    *(bf16x8_t*)(xb + i) = o;
}

// ---------------- GPTQ dequant -> W^T [N][K] bf16 ----------------
__global__ __launch_bounds__(256) void dequant_kernel(const int* __restrict__ qw,
                                                      const int* __restrict__ qz,
                                                      const float* __restrict__ sc,
                                                      __bf16* __restrict__ Wt) {
    __shared__ __align__(16) __bf16 dqT[128 * 136];  // [n][k] pad +8 bf16
    __shared__ float dqS[128];
    __shared__ float dqB[128];
    const int n0 = blockIdx.x * 128;
    const int g  = blockIdx.y;          // group index == k-tile (k0 = g*128)
    const int t  = threadIdx.x;

    if (t < 128) {
        int n = n0 + t;
        float s = sc[(size_t)g * N_DIM + n];
        int z = (qz[(size_t)g * (N_DIM / 8) + (n >> 3)] >> ((n & 7) * 4)) & 15;
        dqS[t] = s;
        dqB[t] = -(float)(z + 1) * s;     // GPTQ +1 zero offset
    }
    __syncthreads();

#pragma unroll
    for (int it = 0; it < 8; ++it) {
        int wi  = it * 256 + t;
        int row = wi >> 7;               // 0..15 (kp sub-row)
        int col = wi & 127;              // n sub-col
        int q = qw[(size_t)(g * 16 + row) * N_DIM + n0 + col];
        float s = dqS[col], b = dqB[col];
        bf16x8_t v;
#pragma unroll
        for (int j = 0; j < 8; ++j) {
            float w = (float)((q >> (4 * j)) & 15);
            v[j] = (__bf16)fmaf(w, s, b);
        }
        *(bf16x8_t*)(&dqT[col * 136 + row * 8]) = v;
    }
    __syncthreads();

    int n_loc = t & 127, half = t >> 7;
    const __bf16* src = &dqT[n_loc * 136 + half * 64];
    __bf16* dst = Wt + (size_t)(n0 + n_loc) * K_DIM + g * GROUP_SZ + half * 64;
#pragma unroll
    for (int i = 0; i < 8; ++i)
        *(bf16x8_t*)(dst + i * 8) = *(const bf16x8_t*)(src + i * 8);
}

// ---------------- 256x256 8-wave 8-phase MFMA GEMM ----------------
__global__ __launch_bounds__(512, 2) void gemm256_kernel(const __bf16* __restrict__ A,
                                                         const __bf16* __restrict__ Bt,
                                                         float* __restrict__ C,
                                                         int mtiles, int ntiles) {
    __shared__ __align__(16) char ldsA[2][256 * 128];   // 64 KB
    __shared__ __align__(16) char ldsB[2][256 * 128];   // 64 KB
    const int tid = threadIdx.x;

    // T1: XCD chunking (bijective: grid % 8 == 0 here) + band supertiling for L3.
    const int nwg = gridDim.x;
    const int bid = blockIdx.x;
    int vid = (nwg & 7) ? bid : ((bid & 7) * (nwg >> 3) + (bid >> 3));
    int mt, nt;
    if ((mtiles & 15) == 0) {
        const int bandsz = 16 * ntiles;
        const int band = vid / bandsz, rem = vid % bandsz;
        nt = rem >> 4;
        mt = (band << 4) + (rem & 15);
    } else {
        mt = vid % mtiles;
        nt = vid / mtiles;
    }

    const char* aPanel = (const char*)A + (size_t)mt * 256 * KB;
    const char* bPanel = (const char*)Bt + (size_t)nt * 256 * KB;

    // Staging offsets (linear LDS dest, inverse-XOR-swizzled global source).
    // f = q*512 + tid -> r = f>>3 in 0..127 (one operand-half), c = f&7.
    int srcO[2], dstO[2];
#pragma unroll
    for (int q = 0; q < 2; ++q) {
        const int f = q * 512 + tid;
        const int r = f >> 3, c = f & 7;
        const int swz = (c * 16) ^ ((r & 7) << 4);
        srcO[q] = r * KB + swz;  dstO[q] = r * 128 + c * 16;
    }

    const int lane = tid & 63;
    const int wid = tid >> 6;
    const int wm = wid >> 2, wn = wid & 3;        // 2 x 4 waves
    const int lr = lane & 15, lq = lane >> 4;
    const int kOff0 = (lq * 16) ^ ((lr & 7) << 4);
    const int kOff1 = (64 + lq * 16) ^ ((lr & 7) << 4);
    const int aRowBase = wm * 128 + lr;           // rows within A-half(wm)
    const int bRowBase = wn * 64 + lr;            // rows within B-half(wn>>1)

    bf16x8_t aF[4][2], bF[4][2];
    f32x4_t acc[8][4];
#pragma unroll
    for (int m = 0; m < 8; ++m)
#pragma unroll
        for (int n = 0; n < 4; ++n)
            acc[m][n] = (f32x4_t){0.f, 0.f, 0.f, 0.f};

// Stage ONE operand-half (rows H*128..H*128+127) of K-tile KT into buffer BUFS.
#define GLA(KT, BUFS, H) do {                                                              \
    async_copy16(aPanel + (size_t)(KT) * 128 + (H) * 128 * KB + srcO[0],                   \
                 &ldsA[BUFS][(H) * 128 * 128] + dstO[0]);                                  \
    async_copy16(aPanel + (size_t)(KT) * 128 + (H) * 128 * KB + srcO[1],                   \
                 &ldsA[BUFS][(H) * 128 * 128] + dstO[1]);                                  \
} while (0)
#define GLB(KT, BUFS, H) do {                                                              \
    async_copy16(bPanel + (size_t)(KT) * 128 + (H) * 128 * KB + srcO[0],                   \
                 &ldsB[BUFS][(H) * 128 * 128] + dstO[0]);                                  \
    async_copy16(bPanel + (size_t)(KT) * 128 + (H) * 128 * KB + srcO[1],                   \
                 &ldsB[BUFS][(H) * 128 * 128] + dstO[1]);                                  \
} while (0)
#define READ_A(MQ, BUFC) do {                                                              \
    _Pragma("unroll") for (int i = 0; i < 4; ++i) {                                        \
        const char* _p = &ldsA[BUFC][(aRowBase + (MQ) * 64 + i * 16) * 128];               \
        aF[i][0] = *(const bf16x8_t*)(_p + kOff0);                                         \
        aF[i][1] = *(const bf16x8_t*)(_p + kOff1);                                         \
    }                                                                                      \
} while (0)
#define READ_B(NQ, BUFC) do {                                                              \
    _Pragma("unroll") for (int j = 0; j < 2; ++j) {                                        \
        const char* _p = &ldsB[BUFC][(bRowBase + ((NQ) * 2 + j) * 16) * 128];              \
        bF[(NQ) * 2 + j][0] = *(const bf16x8_t*)(_p + kOff0);                              \
        bF[(NQ) * 2 + j][1] = *(const bf16x8_t*)(_p + kOff1);                              \
    }                                                                                      \
} while (0)
#define MFMA_QUAD(MQ, NQ) do {                                                             \
    __builtin_amdgcn_s_setprio(1);                                                         \
    _Pragma("unroll") for (int kk = 0; kk < 2; ++kk)                                       \
    _Pragma("unroll") for (int i = 0; i < 4; ++i)                                          \
    _Pragma("unroll") for (int j = 0; j < 2; ++j)                                          \
        acc[(MQ) * 4 + i][(NQ) * 2 + j] = __builtin_amdgcn_mfma_f32_16x16x32_bf16(         \
            aF[i][kk], bF[(NQ) * 2 + j][kk], acc[(MQ) * 4 + i][(NQ) * 2 + j], 0, 0, 0);    \
    __builtin_amdgcn_s_setprio(0);                                                         \
} while (0)
#define BARRIER() asm volatile("s_barrier" ::: "memory")
#define VMCNT4()  asm volatile("s_waitcnt vmcnt(4)" ::: "memory")
#define LGKM0()   asm volatile("s_waitcnt lgkmcnt(0)" ::: "memory")
#define LGKM8()   asm volatile("s_waitcnt lgkmcnt(8)" ::: "memory")

    // Prologue stage stream: tile0 {B0,B1,A0,A1} -> buf0, tile1 {B0,B1} -> buf1.
    // vmcnt(4) leaves tile1's B halves (4 loads) in flight; tile0 fully landed.
    GLB(0, 0, 0); GLB(0, 0, 1); GLA(0, 0, 0); GLA(0, 0, 1);
    GLB(1, 1, 0); GLB(1, 1, 1);
    VMCNT4(); BARRIER();

#pragma unroll 1
    for (int it = 0; it < NTILES_K / 2; ++it) {
        const int b = 2 * it + 1;                          // tile in buf1, phases 5-8
        const int c = (2 * it + 2 < NTILES_K) ? 2 * it + 2 : NTILES_K - 2;  // -> buf0
        const int d = (2 * it + 3 < NTILES_K) ? 2 * it + 3 : NTILES_K - 1;  // -> buf1
        // ---- phases 1-4: compute tile a = 2*it from buf0 ----
        // p1: 12 reads; stage A0(b)->buf1
        READ_A(0, 0); READ_B(0, 0);
        GLA(b, 1, 0);
        LGKM8();
        BARRIER(); LGKM0();
        MFMA_QUAD(0, 0);
        BARRIER();
        // p2: 4 reads; stage A1(b)->buf1
        READ_B(1, 0);
        GLA(b, 1, 1);
        BARRIER(); LGKM0();
        MFMA_QUAD(0, 1);
        BARRIER();
        // p3: 8 reads; stage B0(c)->buf0 (B(a) consumed by p2's lgkm0)
        READ_A(1, 0);
        GLB(c, 0, 0);
        BARRIER(); LGKM0();
        MFMA_QUAD(1, 1);
        BARRIER();
        // p4: 0 reads; stage B1(c)->buf0; counted wait publishes tile b
        GLB(c, 0, 1);
        VMCNT4();
        BARRIER();
        MFMA_QUAD(1, 0);
        BARRIER();
        // ---- phases 5-8: compute tile b from buf1 ----
        // p5: 12 reads; stage A0(c)->buf0 (A(a) consumed by p3's lgkm0)
        READ_A(0, 1); READ_B(0, 1);
        GLA(c, 0, 0);
        LGKM8();
        BARRIER(); LGKM0();
        MFMA_QUAD(0, 0);
        BARRIER();
        // p6: 4 reads; stage A1(c)->buf0
        READ_B(1, 1);
        GLA(c, 0, 1);
        BARRIER(); LGKM0();
        MFMA_QUAD(0, 1);
        BARRIER();
        // p7: 8 reads; stage B0(d)->buf1 (B(b) consumed by p6's lgkm0)
        READ_A(1, 1);
        GLB(d, 1, 0);
        BARRIER(); LGKM0();
        MFMA_QUAD(1, 1);
        BARRIER();
        // p8: 0 reads; stage B1(d)->buf1; counted wait publishes tile c
        GLB(d, 1, 1);
        VMCNT4();
        BARRIER();
        MFMA_QUAD(1, 0);
        BARRIER();
    }

    // Drain tail staging DMAs before the block can retire.
    asm volatile("s_waitcnt vmcnt(0)" ::: "memory");

    // Epilogue: C/D layout col=lane&15, row=(lane>>4)*4+reg.
#pragma unroll
    for (int m = 0; m < 8; ++m) {
        const size_t gr = (size_t)mt * 256 + wm * 128 + m * 16 + lq * 4;
#pragma unroll
        for (int n = 0; n < 4; ++n) {
            const size_t gc = (size_t)nt * 256 + wn * 64 + n * 16 + lr;
            float* cp = C + gr * N_DIM + gc;
#pragma unroll
            for (int rg = 0; rg < 4; ++rg)
                cp[(size_t)rg * N_DIM] = acc[m][n][rg];
        }
    }
}

// ---------------- fallback (ws too small / odd shape): fused fp32 ----------------
__global__ __launch_bounds__(256) void fallback_kernel(const float* __restrict__ x,
                                                       const int* __restrict__ qw,
                                                       const int* __restrict__ qz,
                                                       const float* __restrict__ sc,
                                                       float* __restrict__ out) {
    __shared__ float xrow[K_DIM];
    const int t = blockIdx.y;
    const int n = blockIdx.x * 256 + threadIdx.x;
    for (int i = threadIdx.x; i < K_DIM; i += 256)
        xrow[i] = x[(size_t)t * K_DIM + i];
    __syncthreads();
    if (n >= N_DIM) return;
    float acc = 0.f;
    for (int g = 0; g < K_DIM / GROUP_SZ; ++g) {
        float s = sc[(size_t)g * N_DIM + n];
        int z = (qz[(size_t)g * (N_DIM / 8) + (n >> 3)] >> ((n & 7) * 4)) & 15;
        float b = -(float)(z + 1) * s;
        for (int kp = g * 16; kp < g * 16 + 16; ++kp) {
            int q = qw[(size_t)kp * N_DIM + n];
#pragma unroll
            for (int j = 0; j < 8; ++j) {
                float w = (float)((q >> (4 * j)) & 15);
                acc = fmaf(xrow[kp * 8 + j], fmaf(w, s, b), acc);
            }
        }
    }
    out[(size_t)t * N_DIM + n] = acc;
}

extern "C" void kernel_launch(void* const* d_in, const int* in_sizes, int n_in,
                              void* d_out, int out_size, void* d_ws, size_t ws_size,
                              hipStream_t stream) {
    const float* x  = (const float*)d_in[0];
    const int*   qw = (const int*)d_in[1];
    const int*   qz = (const int*)d_in[2];
    const float* sc = (const float*)d_in[3];
    float* out = (float*)d_out;

    const long T = (long)in_sizes[0] / K_DIM;   // 8192
    const size_t xb_bytes = (size_t)T * K_DIM * sizeof(__bf16);
    const size_t wt_bytes = (size_t)N_DIM * K_DIM * sizeof(__bf16);

    if (ws_size >= xb_bytes + wt_bytes && (T % 256) == 0) {
        __bf16* xb = (__bf16*)d_ws;
        __bf16* Wt = (__bf16*)((char*)d_ws + xb_bytes);
        long total = T * K_DIM;
        long nthr = total / 8;
        convert_x_kernel<<<dim3((unsigned)((nthr + 255) / 256)), dim3(256), 0, stream>>>(x, xb, total);
        dequant_kernel<<<dim3(N_DIM / 128, K_DIM / GROUP_SZ), dim3(256), 0, stream>>>(qw, qz, sc, Wt);
        const int mtiles = (int)(T / 256);          // 32
        const int ntiles = N_DIM / 256;             // 43
        gemm256_kernel<<<dim3((unsigned)(mtiles * ntiles)), dim3(512), 0, stream>>>(xb, Wt, out, mtiles, ntiles);
    } else {
        fallback_kernel<<<dim3(N_DIM / 256 + 1, (unsigned)T), dim3(256), 0, stream>>>(x, qw, qz, sc, out);
    }
}

// Round 8
// 752.885 us; speedup vs baseline: 1.0980x; 1.0980x over previous
//
#include <hip/hip_runtime.h>
#include <hip/hip_bf16.h>
#include <cstdint>
#include <cstddef>

// GPTQ int4 linear: out[T,N] = x[T,K] @ dequant(qweight,qzeros,scales)
// T=8192, K=4096, N=11008, GROUP=128.
// Pipeline: x->bf16, dequant->W^T[N,K] bf16, then 256x256-tile 8-wave MFMA GEMM.
// R8: R3 (best so far: 717us, MfmaUtil 47%) with setprio brackets REMOVED.
// Rationale: s_setprio has unmodeled side effects -> scheduler can't migrate
// the next phase's ds_reads into the MFMA cluster's shadow; m190 measured
// setprio ~0/negative on lockstep GEMM structures anyway. Single-variable A/B.

#define K_DIM 4096
#define N_DIM 11008
#define GROUP_SZ 128
#define KB (K_DIM * 2)        // bytes per row of a K-major bf16 panel
#define NTILES_K (K_DIM / 64) // 64 K-tiles of BK=64

typedef __bf16 bf16x8_t __attribute__((ext_vector_type(8)));
typedef float f32x4_t __attribute__((ext_vector_type(4)));

__device__ __forceinline__ void async_copy16(const void* g, void* l) {
    __builtin_amdgcn_global_load_lds((const __attribute__((address_space(1))) void*)g,
                                     (__attribute__((address_space(3))) void*)l,
                                     16, 0, 0);
}

// ---------------- x fp32 -> bf16 (vectorized) ----------------
__global__ __launch_bounds__(256) void convert_x_kernel(const float* __restrict__ x,
                                                        __bf16* __restrict__ xb,
                                                        long total) {
    long i = ((long)blockIdx.x * 256 + threadIdx.x) * 8;
    if (i >= total) return;
    const float4* p = (const float4*)(x + i);
    float4 u = p[0], v = p[1];
    bf16x8_t o;
    o[0] = (__bf16)u.x; o[1] = (__bf16)u.y; o[2] = (__bf16)u.z; o[3] = (__bf16)u.w;
    o[4] = (__bf16)v.x; o[5] = (__bf16)v.y; o[6] = (__bf16)v.z; o[7] = (__bf16)v.w;
    *(bf16x8_t*)(xb + i) = o;
}

// ---------------- GPTQ dequant -> W^T [N][K] bf16 ----------------
__global__ __launch_bounds__(256) void dequant_kernel(const int* __restrict__ qw,
                                                      const int* __restrict__ qz,
                                                      const float* __restrict__ sc,
                                                      __bf16* __restrict__ Wt) {
    __shared__ __align__(16) __bf16 dqT[128 * 136];  // [n][k] pad +8 bf16
    __shared__ float dqS[128];
    __shared__ float dqB[128];
    const int n0 = blockIdx.x * 128;
    const int g  = blockIdx.y;          // group index == k-tile (k0 = g*128)
    const int t  = threadIdx.x;

    if (t < 128) {
        int n = n0 + t;
        float s = sc[(size_t)g * N_DIM + n];
        int z = (qz[(size_t)g * (N_DIM / 8) + (n >> 3)] >> ((n & 7) * 4)) & 15;
        dqS[t] = s;
        dqB[t] = -(float)(z + 1) * s;     // GPTQ +1 zero offset
    }
    __syncthreads();

#pragma unroll
    for (int it = 0; it < 8; ++it) {
        int wi  = it * 256 + t;
        int row = wi >> 7;               // 0..15 (kp sub-row)
        int col = wi & 127;              // n sub-col
        int q = qw[(size_t)(g * 16 + row) * N_DIM + n0 + col];
        float s = dqS[col], b = dqB[col];
        bf16x8_t v;
#pragma unroll
        for (int j = 0; j < 8; ++j) {
            float w = (float)((q >> (4 * j)) & 15);
            v[j] = (__bf16)fmaf(w, s, b);
        }
        *(bf16x8_t*)(&dqT[col * 136 + row * 8]) = v;
    }
    __syncthreads();

    int n_loc = t & 127, half = t >> 7;
    const __bf16* src = &dqT[n_loc * 136 + half * 64];
    __bf16* dst = Wt + (size_t)(n0 + n_loc) * K_DIM + g * GROUP_SZ + half * 64;
#pragma unroll
    for (int i = 0; i < 8; ++i)
        *(bf16x8_t*)(dst + i * 8) = *(const bf16x8_t*)(src + i * 8);
}

// ---------------- 256x256 8-wave 4-phase MFMA GEMM ----------------
// C[T,N] = A[T,K] * Bt[N,K]^T.  8 waves as 2(M) x 4(N); wave tile 128x64.
// Per K-tile: 4 phases, ONE barrier each:
//   {ds_read subtile | stage 1 quadrant half-tile | counted vmcnt | barrier |
//    16 MFMA (no setprio -> scheduler may interleave next phase's reads)}
// Ledger (2 loads/thread/GL): vmcnt(4)@ph0 guards BQ1(t) for ph1 reads;
// vmcnt(4)@ph1 guards AQ1(t) for ph2; none @ph2; vmcnt(4)@ph3 guards
// AQ0/BQ0(t+1) for next ph0. Never drains to 0 in the loop.
__global__ __launch_bounds__(512, 2) void gemm256_kernel(const __bf16* __restrict__ A,
                                                         const __bf16* __restrict__ Bt,
                                                         float* __restrict__ C,
                                                         int mtiles, int ntiles) {
    __shared__ __align__(16) char ldsA[2][256 * 128];   // 64 KB
    __shared__ __align__(16) char ldsB[2][256 * 128];   // 64 KB
    const int tid = threadIdx.x;

    // T1: XCD chunking (bijective: grid % 8 == 0 here) + band supertiling for L3.
    const int nwg = gridDim.x;
    const int bid = blockIdx.x;
    int vid = (nwg & 7) ? bid : ((bid & 7) * (nwg >> 3) + (bid >> 3));
    int mt, nt;
    if ((mtiles & 15) == 0) {
        const int bandsz = 16 * ntiles;
        const int band = vid / bandsz, rem = vid % bandsz;
        nt = rem >> 4;
        mt = (band << 4) + (rem & 15);
    } else {
        mt = vid % mtiles;
        nt = vid / mtiles;
    }

    const char* aPanel = (const char*)A + (size_t)mt * 256 * KB;
    const char* bPanel = (const char*)Bt + (size_t)nt * 256 * KB;

    // Staging offsets. Quadrant row maps (preserve row&7 == r&7 so the XOR
    // swizzle mask matches the reader's (row&7)<<4):
    //   A-Q0: r + (r&64)   -> rows {0-63,128-191};  A-Q1 = +64
    //   B-Q0: r + (r&~31)  -> rows {0-31,64-95,128-159,192-223}; B-Q1 = +32
    // LDS dest is LINEAR in lane order (global_load_lds constraint); the
    // inverse XOR swizzle is applied to the GLOBAL source (both-sides rule).
    int srcA[2], srcB[2], dstA[2], dstB[2];
#pragma unroll
    for (int q = 0; q < 2; ++q) {
        const int f = q * 512 + tid;
        const int r = f >> 3, c = f & 7;
        const int swz = (c * 16) ^ ((r & 7) << 4);
        const int Ra = r + (r & 64);
        const int Rb = r + (r & ~31);
        srcA[q] = Ra * KB + swz;  dstA[q] = Ra * 128 + c * 16;
        srcB[q] = Rb * KB + swz;  dstB[q] = Rb * 128 + c * 16;
    }

    const int lane = tid & 63;
    const int wid = tid >> 6;
    const int wm = wid >> 2, wn = wid & 3;        // 2 x 4 waves
    const int lr = lane & 15, lq = lane >> 4;
    const int kOff0 = (lq * 16) ^ ((lr & 7) << 4);
    const int kOff1 = (64 + lq * 16) ^ ((lr & 7) << 4);
    const int aRowBase = wm * 128 + lr;           // + mq*64 + i*16
    const int bRowBase = wn * 64 + lr;            // + n*16

    bf16x8_t aF[4][2], bF[4][2];
    f32x4_t acc[8][4];
#pragma unroll
    for (int m = 0; m < 8; ++m)
#pragma unroll
        for (int n = 0; n < 4; ++n)
            acc[m][n] = (f32x4_t){0.f, 0.f, 0.f, 0.f};

#define GL_A(KT, BUFS, ROFF) do {                                                          \
    async_copy16(aPanel + (size_t)(KT) * 128 + (ROFF) * KB + srcA[0],                      \
                 &ldsA[BUFS][(ROFF) * 128] + dstA[0]);                                     \
    async_copy16(aPanel + (size_t)(KT) * 128 + (ROFF) * KB + srcA[1],                      \
                 &ldsA[BUFS][(ROFF) * 128] + dstA[1]);                                     \
} while (0)
#define GL_B(KT, BUFS, ROFF) do {                                                          \
    async_copy16(bPanel + (size_t)(KT) * 128 + (ROFF) * KB + srcB[0],                      \
                 &ldsB[BUFS][(ROFF) * 128] + dstB[0]);                                     \
    async_copy16(bPanel + (size_t)(KT) * 128 + (ROFF) * KB + srcB[1],                      \
                 &ldsB[BUFS][(ROFF) * 128] + dstB[1]);                                     \
} while (0)
#define READ_A(MQ, BUFC) do {                                                              \
    _Pragma("unroll") for (int i = 0; i < 4; ++i) {                                        \
        const char* _p = &ldsA[BUFC][(aRowBase + (MQ) * 64 + i * 16) * 128];               \
        aF[i][0] = *(const bf16x8_t*)(_p + kOff0);                                         \
        aF[i][1] = *(const bf16x8_t*)(_p + kOff1);                                         \
    }                                                                                      \
} while (0)
#define READ_B(NQ, BUFC) do {                                                              \
    _Pragma("unroll") for (int j = 0; j < 2; ++j) {                                        \
        const char* _p = &ldsB[BUFC][(bRowBase + ((NQ) * 2 + j) * 16) * 128];              \
        bF[(NQ) * 2 + j][0] = *(const bf16x8_t*)(_p + kOff0);                              \
        bF[(NQ) * 2 + j][1] = *(const bf16x8_t*)(_p + kOff1);                              \
    }                                                                                      \
} while (0)
// kk OUTER: same-accumulator MFMAs are 8 apart. NO setprio bracket.
#define MFMA_QUAD(MQ, NQ) do {                                                             \
    _Pragma("unroll") for (int kk = 0; kk < 2; ++kk)                                       \
    _Pragma("unroll") for (int i = 0; i < 4; ++i)                                          \
    _Pragma("unroll") for (int j = 0; j < 2; ++j)                                          \
        acc[(MQ) * 4 + i][(NQ) * 2 + j] = __builtin_amdgcn_mfma_f32_16x16x32_bf16(         \
            aF[i][kk], bF[(NQ) * 2 + j][kk], acc[(MQ) * 4 + i][(NQ) * 2 + j], 0, 0, 0);    \
} while (0)
#define BARRIER() asm volatile("s_barrier" ::: "memory")
#define VMCNT4()  asm volatile("s_waitcnt vmcnt(4)" ::: "memory")

#define KTILE(BUFC, KTS) do {                                                              \
    /* ph0: quad (0,0) */                                                                  \
    READ_A(0, BUFC); READ_B(0, BUFC);                                                      \
    GL_A(KTS, (BUFC) ^ 1, 0);                                                              \
    VMCNT4(); BARRIER();                                                                   \
    MFMA_QUAD(0, 0);                                                                       \
    /* ph1: quad (0,1) */                                                                  \
    READ_B(1, BUFC);                                                                       \
    GL_B(KTS, (BUFC) ^ 1, 0);                                                              \
    VMCNT4(); BARRIER();                                                                   \
    MFMA_QUAD(0, 1);                                                                       \
    /* ph2: quad (1,1) */                                                                  \
    READ_A(1, BUFC);                                                                       \
    GL_B(KTS, (BUFC) ^ 1, 32);                                                             \
    BARRIER();                                                                             \
    MFMA_QUAD(1, 1);                                                                       \
    /* ph3: quad (1,0) — A(mq1), B(nq0) still in regs */                                   \
    GL_A(KTS, (BUFC) ^ 1, 64);                                                             \
    VMCNT4(); BARRIER();                                                                   \
    MFMA_QUAD(1, 0);                                                                       \
} while (0)

    // Prologue: stage tile 0 fully (order AQ0,BQ0,BQ1,AQ1), guarantee AQ0+BQ0.
    GL_A(0, 0, 0); GL_B(0, 0, 0); GL_B(0, 0, 32); GL_A(0, 0, 64);
    VMCNT4(); BARRIER();

#pragma unroll 1
    for (int kt = 0; kt < NTILES_K; kt += 2) {
        const int ks0 = kt + 1;                                   // < NTILES_K always
        const int ks1 = (kt + 2 < NTILES_K) ? kt + 2 : kt + 1;    // tail: restage (harmless)
        KTILE(0, ks0);
        KTILE(1, ks1);
    }

    // Drain tail staging DMAs before the block can retire.
    asm volatile("s_waitcnt vmcnt(0)" ::: "memory");

    // Epilogue: C/D layout col=lane&15, row=(lane>>4)*4+reg.
#pragma unroll
    for (int m = 0; m < 8; ++m) {
        const size_t gr = (size_t)mt * 256 + wm * 128 + m * 16 + lq * 4;
#pragma unroll
        for (int n = 0; n < 4; ++n) {
            const size_t gc = (size_t)nt * 256 + wn * 64 + n * 16 + lr;
            float* cp = C + gr * N_DIM + gc;
#pragma unroll
            for (int rg = 0; rg < 4; ++rg)
                cp[(size_t)rg * N_DIM] = acc[m][n][rg];
        }
    }
}

// ---------------- fallback (ws too small / odd shape): fused fp32 ----------------
__global__ __launch_bounds__(256) void fallback_kernel(const float* __restrict__ x,
                                                       const int* __restrict__ qw,
                                                       const int* __restrict__ qz,
                                                       const float* __restrict__ sc,
                                                       float* __restrict__ out) {
    __shared__ float xrow[K_DIM];
    const int t = blockIdx.y;
    const int n = blockIdx.x * 256 + threadIdx.x;
    for (int i = threadIdx.x; i < K_DIM; i += 256)
        xrow[i] = x[(size_t)t * K_DIM + i];
    __syncthreads();
    if (n >= N_DIM) return;
    float acc = 0.f;
    for (int g = 0; g < K_DIM / GROUP_SZ; ++g) {
        float s = sc[(size_t)g * N_DIM + n];
        int z = (qz[(size_t)g * (N_DIM / 8) + (n >> 3)] >> ((n & 7) * 4)) & 15;
        float b = -(float)(z + 1) * s;
        for (int kp = g * 16; kp < g * 16 + 16; ++kp) {
            int q = qw[(size_t)kp * N_DIM + n];
#pragma unroll
            for (int j = 0; j < 8; ++j) {
                float w = (float)((q >> (4 * j)) & 15);
                acc = fmaf(xrow[kp * 8 + j], fmaf(w, s, b), acc);
            }
        }
    }
    out[(size_t)t * N_DIM + n] = acc;
}

extern "C" void kernel_launch(void* const* d_in, const int* in_sizes, int n_in,
                              void* d_out, int out_size, void* d_ws, size_t ws_size,
                              hipStream_t stream) {
    const float* x  = (const float*)d_in[0];
    const int*   qw = (const int*)d_in[1];
    const int*   qz = (const int*)d_in[2];
    const float* sc = (const float*)d_in[3];
    float* out = (float*)d_out;

    const long T = (long)in_sizes[0] / K_DIM;   // 8192
    const size_t xb_bytes = (size_t)T * K_DIM * sizeof(__bf16);
    const size_t wt_bytes = (size_t)N_DIM * K_DIM * sizeof(__bf16);

    if (ws_size >= xb_bytes + wt_bytes && (T % 256) == 0) {
        __bf16* xb = (__bf16*)d_ws;
        __bf16* Wt = (__bf16*)((char*)d_ws + xb_bytes);
        long total = T * K_DIM;
        long nthr = total / 8;
        convert_x_kernel<<<dim3((unsigned)((nthr + 255) / 256)), dim3(256), 0, stream>>>(x, xb, total);
        dequant_kernel<<<dim3(N_DIM / 128, K_DIM / GROUP_SZ), dim3(256), 0, stream>>>(qw, qz, sc, Wt);
        const int mtiles = (int)(T / 256);          // 32
        const int ntiles = N_DIM / 256;             // 43
        gemm256_kernel<<<dim3((unsigned)(mtiles * ntiles)), dim3(512), 0, stream>>>(xb, Wt, out, mtiles, ntiles);
    } else {
        fallback_kernel<<<dim3(N_DIM / 256 + 1, (unsigned)T), dim3(256), 0, stream>>>(x, qw, qz, sc, out);
    }
}

// Round 9
// 728.971 us; speedup vs baseline: 1.1340x; 1.0328x over previous
//
#include <hip/hip_runtime.h>
#include <hip/hip_bf16.h>
#include <cstdint>
#include <cstddef>

// GPTQ int4 linear: out[T,N] = x[T,K] @ dequant(qweight,qzeros,scales)
// T=8192, K=4096, N=11008, GROUP=128.
// Pipeline: x->bf16, dequant->W^T[N,K] bf16, then 256x256-tile 8-wave MFMA GEMM.
// R9: R8's K-tile structure unchanged; work distribution becomes dynamic
// persistent tiles (grid=256, atomic counter) to remove the 6-round dispatch
// quantization (1376 = 5.375 x 256 -> last round 37.5% occupied = 10.4% idle).
// Cross-tile staging: kt=63 stages the NEXT tile's kt0 into buf0 (parity
// continues), so epilogue stores hide the next tile's HBM latency.

#define K_DIM 4096
#define N_DIM 11008
#define GROUP_SZ 128
#define KB (K_DIM * 2)        // bytes per row of a K-major bf16 panel
#define NTILES_K (K_DIM / 64) // 64 K-tiles of BK=64

typedef __bf16 bf16x8_t __attribute__((ext_vector_type(8)));
typedef float f32x4_t __attribute__((ext_vector_type(4)));

__device__ __forceinline__ void async_copy16(const void* g, void* l) {
    __builtin_amdgcn_global_load_lds((const __attribute__((address_space(1))) void*)g,
                                     (__attribute__((address_space(3))) void*)l,
                                     16, 0, 0);
}

// ---------------- x fp32 -> bf16 (vectorized) + counter reset ----------------
__global__ __launch_bounds__(256) void convert_x_kernel(const float* __restrict__ x,
                                                        __bf16* __restrict__ xb,
                                                        long total,
                                                        unsigned* __restrict__ counter) {
    if (counter && blockIdx.x == 0 && threadIdx.x == 0) counter[0] = 0u;
    long i = ((long)blockIdx.x * 256 + threadIdx.x) * 8;
    if (i >= total) return;
    const float4* p = (const float4*)(x + i);
    float4 u = p[0], v = p[1];
    bf16x8_t o;
    o[0] = (__bf16)u.x; o[1] = (__bf16)u.y; o[2] = (__bf16)u.z; o[3] = (__bf16)u.w;
    o[4] = (__bf16)v.x; o[5] = (__bf16)v.y; o[6] = (__bf16)v.z; o[7] = (__bf16)v.w;
    *(bf16x8_t*)(xb + i) = o;
}

// ---------------- GPTQ dequant -> W^T [N][K] bf16 ----------------
__global__ __launch_bounds__(256) void dequant_kernel(const int* __restrict__ qw,
                                                      const int* __restrict__ qz,
                                                      const float* __restrict__ sc,
                                                      __bf16* __restrict__ Wt) {
    __shared__ __align__(16) __bf16 dqT[128 * 136];  // [n][k] pad +8 bf16
    __shared__ float dqS[128];
    __shared__ float dqB[128];
    const int n0 = blockIdx.x * 128;
    const int g  = blockIdx.y;          // group index == k-tile (k0 = g*128)
    const int t  = threadIdx.x;

    if (t < 128) {
        int n = n0 + t;
        float s = sc[(size_t)g * N_DIM + n];
        int z = (qz[(size_t)g * (N_DIM / 8) + (n >> 3)] >> ((n & 7) * 4)) & 15;
        dqS[t] = s;
        dqB[t] = -(float)(z + 1) * s;     // GPTQ +1 zero offset
    }
    __syncthreads();

#pragma unroll
    for (int it = 0; it < 8; ++it) {
        int wi  = it * 256 + t;
        int row = wi >> 7;               // 0..15 (kp sub-row)
        int col = wi & 127;              // n sub-col
        int q = qw[(size_t)(g * 16 + row) * N_DIM + n0 + col];
        float s = dqS[col], b = dqB[col];
        bf16x8_t v;
#pragma unroll
        for (int j = 0; j < 8; ++j) {
            float w = (float)((q >> (4 * j)) & 15);
            v[j] = (__bf16)fmaf(w, s, b);
        }
        *(bf16x8_t*)(&dqT[col * 136 + row * 8]) = v;
    }
    __syncthreads();

    int n_loc = t & 127, half = t >> 7;
    const __bf16* src = &dqT[n_loc * 136 + half * 64];
    __bf16* dst = Wt + (size_t)(n0 + n_loc) * K_DIM + g * GROUP_SZ + half * 64;
#pragma unroll
    for (int i = 0; i < 8; ++i)
        *(bf16x8_t*)(dst + i * 8) = *(const bf16x8_t*)(src + i * 8);
}

__device__ __forceinline__ void map_tile(int vid, int mtiles, int ntiles,
                                         int& mt, int& nt) {
    if ((mtiles & 15) == 0) {          // band supertiling for L3 locality
        const int bandsz = 16 * ntiles;
        const int band = vid / bandsz, rem = vid % bandsz;
        nt = rem >> 4;
        mt = (band << 4) + (rem & 15);
    } else {
        mt = vid % mtiles;
        nt = vid / mtiles;
    }
}

// ---------------- 256x256 8-wave 4-phase MFMA GEMM (persistent) ----------------
// K-tile structure identical to R8 (best verified): 4 phases, 1 barrier each,
// quadrant-aligned counted vmcnt(4) ledger, no setprio.
__global__ __launch_bounds__(512, 2) void gemm256_kernel(const __bf16* __restrict__ A,
                                                         const __bf16* __restrict__ Bt,
                                                         float* __restrict__ C,
                                                         int mtiles, int ntiles,
                                                         unsigned* counter, int ntotal) {
    __shared__ __align__(16) char ldsA[2][256 * 128];   // 64 KB
    __shared__ __align__(16) char ldsB[2][256 * 128];   // 64 KB
    __shared__ int sVid;
    const int tid = threadIdx.x;

    // Staging offsets. Quadrant row maps (preserve row&7 == r&7 so the XOR
    // swizzle mask matches the reader's (row&7)<<4):
    //   A-Q0: r + (r&64)   -> rows {0-63,128-191};  A-Q1 = +64
    //   B-Q0: r + (r&~31)  -> rows {0-31,64-95,128-159,192-223}; B-Q1 = +32
    // LDS dest is LINEAR in lane order (global_load_lds constraint); the
    // inverse XOR swizzle is applied to the GLOBAL source (both-sides rule).
    int srcA[2], srcB[2], dstA[2], dstB[2];
#pragma unroll
    for (int q = 0; q < 2; ++q) {
        const int f = q * 512 + tid;
        const int r = f >> 3, c = f & 7;
        const int swz = (c * 16) ^ ((r & 7) << 4);
        const int Ra = r + (r & 64);
        const int Rb = r + (r & ~31);
        srcA[q] = Ra * KB + swz;  dstA[q] = Ra * 128 + c * 16;
        srcB[q] = Rb * KB + swz;  dstB[q] = Rb * 128 + c * 16;
    }

    const int lane = tid & 63;
    const int wid = tid >> 6;
    const int wm = wid >> 2, wn = wid & 3;        // 2 x 4 waves
    const int lr = lane & 15, lq = lane >> 4;
    const int kOff0 = (lq * 16) ^ ((lr & 7) << 4);
    const int kOff1 = (64 + lq * 16) ^ ((lr & 7) << 4);
    const int aRowBase = wm * 128 + lr;           // + mq*64 + i*16
    const int bRowBase = wn * 64 + lr;            // + n*16

    bf16x8_t aF[4][2], bF[4][2];
    f32x4_t acc[8][4];

#define GL_A(AP, KT, BUFS, ROFF) do {                                                      \
    async_copy16((AP) + (size_t)(KT) * 128 + (ROFF) * KB + srcA[0],                        \
                 &ldsA[BUFS][(ROFF) * 128] + dstA[0]);                                     \
    async_copy16((AP) + (size_t)(KT) * 128 + (ROFF) * KB + srcA[1],                        \
                 &ldsA[BUFS][(ROFF) * 128] + dstA[1]);                                     \
} while (0)
#define GL_B(BP, KT, BUFS, ROFF) do {                                                      \
    async_copy16((BP) + (size_t)(KT) * 128 + (ROFF) * KB + srcB[0],                        \
                 &ldsB[BUFS][(ROFF) * 128] + dstB[0]);                                     \
    async_copy16((BP) + (size_t)(KT) * 128 + (ROFF) * KB + srcB[1],                        \
                 &ldsB[BUFS][(ROFF) * 128] + dstB[1]);                                     \
} while (0)
#define READ_A(MQ, BUFC) do {                                                              \
    _Pragma("unroll") for (int i = 0; i < 4; ++i) {                                        \
        const char* _p = &ldsA[BUFC][(aRowBase + (MQ) * 64 + i * 16) * 128];               \
        aF[i][0] = *(const bf16x8_t*)(_p + kOff0);                                         \
        aF[i][1] = *(const bf16x8_t*)(_p + kOff1);                                         \
    }                                                                                      \
} while (0)
#define READ_B(NQ, BUFC) do {                                                              \
    _Pragma("unroll") for (int j = 0; j < 2; ++j) {                                        \
        const char* _p = &ldsB[BUFC][(bRowBase + ((NQ) * 2 + j) * 16) * 128];              \
        bF[(NQ) * 2 + j][0] = *(const bf16x8_t*)(_p + kOff0);                              \
        bF[(NQ) * 2 + j][1] = *(const bf16x8_t*)(_p + kOff1);                              \
    }                                                                                      \
} while (0)
#define MFMA_QUAD(MQ, NQ) do {                                                             \
    _Pragma("unroll") for (int kk = 0; kk < 2; ++kk)                                       \
    _Pragma("unroll") for (int i = 0; i < 4; ++i)                                          \
    _Pragma("unroll") for (int j = 0; j < 2; ++j)                                          \
        acc[(MQ) * 4 + i][(NQ) * 2 + j] = __builtin_amdgcn_mfma_f32_16x16x32_bf16(         \
            aF[i][kk], bF[(NQ) * 2 + j][kk], acc[(MQ) * 4 + i][(NQ) * 2 + j], 0, 0, 0);    \
} while (0)
#define BARRIER() asm volatile("s_barrier" ::: "memory")
#define VMCNT4()  asm volatile("s_waitcnt vmcnt(4)" ::: "memory")
#define VMCNT0()  asm volatile("s_waitcnt vmcnt(0)" ::: "memory")

// Steady K-tile: compute from BUFC, stage K-tile KTS quadrants into BUFC^1.
#define KTILE(AP, BP, BUFC, KTS) do {                                                      \
    READ_A(0, BUFC); READ_B(0, BUFC);                                                      \
    GL_A(AP, KTS, (BUFC) ^ 1, 0);                                                          \
    VMCNT4(); BARRIER();                                                                   \
    MFMA_QUAD(0, 0);                                                                       \
    READ_B(1, BUFC);                                                                       \
    GL_B(BP, KTS, (BUFC) ^ 1, 0);                                                          \
    VMCNT4(); BARRIER();                                                                   \
    MFMA_QUAD(0, 1);                                                                       \
    READ_A(1, BUFC);                                                                       \
    GL_B(BP, KTS, (BUFC) ^ 1, 32);                                                         \
    BARRIER();                                                                             \
    MFMA_QUAD(1, 1);                                                                       \
    GL_A(AP, KTS, (BUFC) ^ 1, 64);                                                         \
    VMCNT4(); BARRIER();                                                                   \
    MFMA_QUAD(1, 0);                                                                       \
} while (0)

// Final K-tile (kt=63, buf1): stage NEXT tile's kt0 (panels NAP/NBP) into buf0.
// If !HAVE, drain at ph0 (vmcnt(0)); later vmcnt(4)s become no-ops.
#define KTILE_LAST(NAP, NBP, HAVE) do {                                                    \
    READ_A(0, 1); READ_B(0, 1);                                                            \
    if (HAVE) { GL_A(NAP, 0, 0, 0); VMCNT4(); } else { VMCNT0(); }                         \
    BARRIER();                                                                             \
    MFMA_QUAD(0, 0);                                                                       \
    READ_B(1, 1);                                                                          \
    if (HAVE) GL_B(NBP, 0, 0, 0);                                                          \
    VMCNT4(); BARRIER();                                                                   \
    MFMA_QUAD(0, 1);                                                                       \
    READ_A(1, 1);                                                                          \
    if (HAVE) GL_B(NBP, 0, 0, 32);                                                         \
    BARRIER();                                                                             \
    MFMA_QUAD(1, 1);                                                                       \
    if (HAVE) GL_A(NAP, 0, 0, 64);                                                         \
    VMCNT4(); BARRIER();                                                                   \
    MFMA_QUAD(1, 0);                                                                       \
} while (0)

    // First tile grab.
    int vid;
    if (counter) {
        if (tid == 0) sVid = (int)atomicAdd(counter, 1u);
        __syncthreads();
        vid = sVid;
    } else {
        const int nwg = gridDim.x, bid = blockIdx.x;
        vid = (nwg & 7) ? bid : ((bid & 7) * (nwg >> 3) + (bid >> 3));
    }

    bool first = true;
    while (vid < ntotal) {
        int mt, nt;
        map_tile(vid, mtiles, ntiles, mt, nt);
        const char* aPanel = (const char*)A + (size_t)mt * 256 * KB;
        const char* bPanel = (const char*)Bt + (size_t)nt * 256 * KB;

        if (first) {   // stage kt0 quadrants -> buf0 (else staged by prev KTILE_LAST)
            GL_A(aPanel, 0, 0, 0); GL_B(bPanel, 0, 0, 0);
            GL_B(bPanel, 0, 0, 32); GL_A(aPanel, 0, 0, 64);
            VMCNT4(); BARRIER();
            first = false;
        }

#pragma unroll
        for (int m = 0; m < 8; ++m)
#pragma unroll
            for (int n = 0; n < 4; ++n)
                acc[m][n] = (f32x4_t){0.f, 0.f, 0.f, 0.f};

#pragma unroll 1
        for (int kt = 0; kt < NTILES_K - 2; kt += 2) {
            KTILE(aPanel, bPanel, 0, kt + 1);
            KTILE(aPanel, bPanel, 1, kt + 2);
        }
        KTILE(aPanel, bPanel, 0, NTILES_K - 1);   // kt=62, stages kt63 -> buf1

        // Grab next tile before the final K-tile so its kt0 staging overlaps.
        int nvid;
        if (counter) {
            if (tid == 0) sVid = (int)atomicAdd(counter, 1u);
            __syncthreads();
            nvid = sVid;
        } else {
            nvid = ntotal;
        }
        const bool have = nvid < ntotal;
        const char* naP = aPanel;
        const char* nbP = bPanel;
        if (have) {
            int nmt, nnt;
            map_tile(nvid, mtiles, ntiles, nmt, nnt);
            naP = (const char*)A + (size_t)nmt * 256 * KB;
            nbP = (const char*)Bt + (size_t)nnt * 256 * KB;
        }
        KTILE_LAST(naP, nbP, have);               // kt=63, stages next kt0 -> buf0

        // Epilogue: C/D layout col=lane&15, row=(lane>>4)*4+reg.
        // Overlaps the next tile's kt0 HBM latency.
#pragma unroll
        for (int m = 0; m < 8; ++m) {
            const size_t gr = (size_t)mt * 256 + wm * 128 + m * 16 + lq * 4;
#pragma unroll
            for (int n = 0; n < 4; ++n) {
                const size_t gc = (size_t)nt * 256 + wn * 64 + n * 16 + lr;
                float* cp = C + gr * N_DIM + gc;
#pragma unroll
                for (int rg = 0; rg < 4; ++rg)
                    cp[(size_t)rg * N_DIM] = acc[m][n][rg];
            }
        }

        vid = nvid;
    }
}

// ---------------- fallback (ws too small / odd shape): fused fp32 ----------------
__global__ __launch_bounds__(256) void fallback_kernel(const float* __restrict__ x,
                                                       const int* __restrict__ qw,
                                                       const int* __restrict__ qz,
                                                       const float* __restrict__ sc,
                                                       float* __restrict__ out) {
    __shared__ float xrow[K_DIM];
    const int t = blockIdx.y;
    const int n = blockIdx.x * 256 + threadIdx.x;
    for (int i = threadIdx.x; i < K_DIM; i += 256)
        xrow[i] = x[(size_t)t * K_DIM + i];
    __syncthreads();
    if (n >= N_DIM) return;
    float acc = 0.f;
    for (int g = 0; g < K_DIM / GROUP_SZ; ++g) {
        float s = sc[(size_t)g * N_DIM + n];
        int z = (qz[(size_t)g * (N_DIM / 8) + (n >> 3)] >> ((n & 7) * 4)) & 15;
        float b = -(float)(z + 1) * s;
        for (int kp = g * 16; kp < g * 16 + 16; ++kp) {
            int q = qw[(size_t)kp * N_DIM + n];
#pragma unroll
            for (int j = 0; j < 8; ++j) {
                float w = (float)((q >> (4 * j)) & 15);
                acc = fmaf(xrow[kp * 8 + j], fmaf(w, s, b), acc);
            }
        }
    }
    out[(size_t)t * N_DIM + n] = acc;
}

extern "C" void kernel_launch(void* const* d_in, const int* in_sizes, int n_in,
                              void* d_out, int out_size, void* d_ws, size_t ws_size,
                              hipStream_t stream) {
    const float* x  = (const float*)d_in[0];
    const int*   qw = (const int*)d_in[1];
    const int*   qz = (const int*)d_in[2];
    const float* sc = (const float*)d_in[3];
    float* out = (float*)d_out;

    const long T = (long)in_sizes[0] / K_DIM;   // 8192
    const size_t xb_bytes = (size_t)T * K_DIM * sizeof(__bf16);
    const size_t wt_bytes = (size_t)N_DIM * K_DIM * sizeof(__bf16);
    const size_t cnt_off  = (xb_bytes + wt_bytes + 255) & ~(size_t)255;

    if (ws_size >= xb_bytes + wt_bytes && (T % 256) == 0) {
        __bf16* xb = (__bf16*)d_ws;
        __bf16* Wt = (__bf16*)((char*)d_ws + xb_bytes);
        unsigned* counter = (ws_size >= cnt_off + 256)
                          ? (unsigned*)((char*)d_ws + cnt_off) : nullptr;
        long total = T * K_DIM;
        long nthr = total / 8;
        convert_x_kernel<<<dim3((unsigned)((nthr + 255) / 256)), dim3(256), 0, stream>>>(x, xb, total, counter);
        dequant_kernel<<<dim3(N_DIM / 128, K_DIM / GROUP_SZ), dim3(256), 0, stream>>>(qw, qz, sc, Wt);
        const int mtiles = (int)(T / 256);          // 32
        const int ntiles = N_DIM / 256;             // 43
        const int ntotal = mtiles * ntiles;         // 1376
        const unsigned grid = counter ? 256u : (unsigned)ntotal;
        gemm256_kernel<<<dim3(grid), dim3(512), 0, stream>>>(xb, Wt, out, mtiles, ntiles, counter, ntotal);
    } else {
        fallback_kernel<<<dim3(N_DIM / 256 + 1, (unsigned)T), dim3(256), 0, stream>>>(x, qw, qz, sc, out);
    }
}